// Round 15
// baseline (105.191 us; speedup 1.0000x reference)
//
#include <hip/hip_runtime.h>

// FFF tree traversal, round 15: de-serialize the level chain (1 row/wave —
// ILP2 is triple-refuted: r2/r5/r6 spilled, r14 lost occupancy+overlap).
//  (1) Both-children w1 prefetch (w1 ONLY — r11's regression was doubling
//      w1 AND w2): children addresses depend on node_l, not the sign, so
//      both gathers issue at the level top; cndmask-select after the
//      reduce. Sign->gather leaves the critical chain. w1 traffic 720 MB
//      = r13's proven-sustainable total.
//  (2) w2/y-accum moved OUT of the loop: traversal is fully unrolled with
//      uniform scores/nodes in SGPRs (tiny body -> no r7-style spill);
//      epilogue issues ALL 11 w2 gathers upfront (indices known -> pure
//      MLP) then one dense accum block. w2 stays 360 MB single-node.
// Frozen: i8 x-quant + sdot4 dot, DPP reduces, EPS=0.035 fp32 fallback
// (x reloaded), biased-u8 w2 + corr, nt x loads, plain y stores.

typedef float        f32x4 __attribute__((ext_vector_type(4)));
typedef unsigned int u32x4 __attribute__((ext_vector_type(4)));

#define FFF_BATCH  32768
#define FFF_NIN    1024
#define FFF_NOUT   1024
#define FFF_LEVELS 11
#define FFF_NODES  2047
#define FFF_EPS    0.035f

__device__ __forceinline__ f32x4 ld_nt4f(const f32x4* p) { return __builtin_nontemporal_load(p); }
__device__ __forceinline__ float ub(unsigned d, int k) {
    return (float)((d >> (8 * k)) & 0xffu);   // -> v_cvt_f32_ubyte[k]
}

__device__ __forceinline__ int sdot4(unsigned a, unsigned b, int c) {
#if __has_builtin(__builtin_amdgcn_sdot4)
    return __builtin_amdgcn_sdot4((int)a, (int)b, c, false);
#else
#pragma unroll
    for (int k = 0; k < 4; ++k) {
        const int ai = (int)(a << (24 - 8 * k)) >> 24;
        const int bi = (int)(b << (24 - 8 * k)) >> 24;
        c += ai * bi;
    }
    return c;
#endif
}

template<int CTRL>
__device__ __forceinline__ float dpp_add(float v) {
    const int t = __builtin_amdgcn_update_dpp(0, __float_as_int(v), CTRL, 0xF, 0xF, true);
    return v + __int_as_float(t);
}
__device__ __forceinline__ float wave_sum(float v) {
    v = dpp_add<0x111>(v); v = dpp_add<0x112>(v);
    v = dpp_add<0x114>(v); v = dpp_add<0x118>(v);
    v = dpp_add<0x142>(v); v = dpp_add<0x143>(v);
    return __int_as_float(__builtin_amdgcn_readlane(__float_as_int(v), 63));
}
template<int CTRL>
__device__ __forceinline__ int dpp_addi(int v) {
    return v + __builtin_amdgcn_update_dpp(0, v, CTRL, 0xF, 0xF, true);
}
__device__ __forceinline__ int wave_sum_i(int v) {
    v = dpp_addi<0x111>(v); v = dpp_addi<0x112>(v);
    v = dpp_addi<0x114>(v); v = dpp_addi<0x118>(v);
    v = dpp_addi<0x142>(v); v = dpp_addi<0x143>(v);
    return __builtin_amdgcn_readlane(v, 63);
}
template<int CTRL>
__device__ __forceinline__ float dpp_max(float v) {
    const int t = __builtin_amdgcn_update_dpp(0, __float_as_int(v), CTRL, 0xF, 0xF, true);
    return fmaxf(v, __int_as_float(t));
}
__device__ __forceinline__ float wave_max(float v) {   // v >= 0
    v = dpp_max<0x111>(v); v = dpp_max<0x112>(v);
    v = dpp_max<0x114>(v); v = dpp_max<0x118>(v);
    v = dpp_max<0x142>(v); v = dpp_max<0x143>(v);
    return __int_as_float(__builtin_amdgcn_readlane(__float_as_int(v), 63));
}

// ---- prep: w1 -> signed i8, w2 -> biased u8 (one block per node) ----
// byte b = 4*t + k of node's 1024B row <- src elem 256*(t&3) + 4*(t>>2) + k,
// so in main, lane's dwords 4*lane..+3 pair with xq[c][k] <- x[256c+4*lane+k].
__global__ void fff_quant_u8(const float* __restrict__ w1, const float* __restrict__ w2,
                             unsigned char* __restrict__ q1, unsigned char* __restrict__ q2,
                             float* __restrict__ s1, float* __restrict__ s2)
{
    const int node = blockIdx.x;
    const int t    = threadIdx.x;          // 256
    const int wave = t >> 6;
    const int lane = t & 63;

    const f32x4* r1 = reinterpret_cast<const f32x4*>(w1 + (size_t)node * FFF_NIN);
    const f32x4* r2 = reinterpret_cast<const f32x4*>(w2 + (size_t)node * FFF_NOUT);
    const int si = 64 * (t & 3) + (t >> 2);
    const f32x4 v1 = r1[si];
    const f32x4 v2 = r2[si];

    float m1 = 0.f, m2 = 0.f;
#pragma unroll
    for (int k = 0; k < 4; ++k) {
        m1 = fmaxf(m1, fabsf(v1[k]));
        m2 = fmaxf(m2, fabsf(v2[k]));
    }
#pragma unroll
    for (int m = 1; m < 64; m <<= 1) {
        m1 = fmaxf(m1, __shfl_xor(m1, m, 64));
        m2 = fmaxf(m2, __shfl_xor(m2, m, 64));
    }
    __shared__ float sm1[4], sm2[4];
    if (lane == 0) { sm1[wave] = m1; sm2[wave] = m2; }
    __syncthreads();
    m1 = fmaxf(fmaxf(sm1[0], sm1[1]), fmaxf(sm1[2], sm1[3]));
    m2 = fmaxf(fmaxf(sm2[0], sm2[1]), fmaxf(sm2[2], sm2[3]));

    const float st1 = (m1 > 0.f) ? m1 / 127.f : 1.f;
    const float st2 = (m2 > 0.f) ? m2 / 127.f : 1.f;
    if (t == 0) { s1[node] = st1; s2[node] = st2; }

    unsigned d1 = 0, d2 = 0;
#pragma unroll
    for (int k = 0; k < 4; ++k) {
        const int i1 = (int)rintf(v1[k] / st1);         // signed, [-127,127]
        const int u2 = (int)rintf(v2[k] / st2) + 128;   // biased, [1,255]
        d1 |= ((unsigned)i1 & 0xffu) << (8 * k);
        d2 |= ((unsigned)u2 & 0xffu) << (8 * k);
    }
    reinterpret_cast<unsigned*>(q1)[(size_t)node * 256 + t] = d1;
    reinterpret_cast<unsigned*>(q2)[(size_t)node * 256 + t] = d2;
}

// ---- main fused kernel: 1 row/wave; pipelined traversal + MLP epilogue ----
__global__ __launch_bounds__(256, 4) void fff_main_u8(
    const float*         __restrict__ x,
    const unsigned char* __restrict__ q1,
    const float*         __restrict__ s1,
    const float*         __restrict__ w1f,   // fp32 w1 for the EPS fallback
    const unsigned char* __restrict__ q2,
    const float*         __restrict__ s2,
    float*               __restrict__ y)
{
    const int row  = blockIdx.x * 4 + (threadIdx.x >> 6);
    const int lane = threadIdx.x & 63;

    const f32x4* x4 = reinterpret_cast<const f32x4*>(x + (size_t)row * FFF_NIN);

    // i8 quantization of x (fp32 x not kept live; fallback reloads)
    unsigned xq[4];
    float stx;
    {
        f32x4 xv[4];
#pragma unroll
        for (int c = 0; c < 4; ++c) xv[c] = ld_nt4f(&x4[c * 64 + lane]);
        float mx = 0.f;
#pragma unroll
        for (int c = 0; c < 4; ++c)
#pragma unroll
            for (int k = 0; k < 4; ++k) mx = fmaxf(mx, fabsf(xv[c][k]));
        mx = wave_max(mx);
        stx = (mx > 0.f) ? mx / 127.f : 1.f;
        const float inv = (mx > 0.f) ? 127.f / mx : 0.f;
#pragma unroll
        for (int c = 0; c < 4; ++c) {
            unsigned pk = 0;
#pragma unroll
            for (int k = 0; k < 4; ++k)
                pk |= ((unsigned)(int)rintf(xv[c][k] * inv) & 0xffu) << (8 * k);
            xq[c] = pk;
        }
    }

    const u32x4* q1v = reinterpret_cast<const u32x4*>(q1);  // node*64 + lane
    const u32x4* q2v = reinterpret_cast<const u32x4*>(q2);

    // ---- traversal: fully unrolled, uniform scores/nodes (SGPR) ----
    float sc[FFF_LEVELS];
    int   nd[FFF_LEVELS];
    u32x4 d1c = q1v[lane];      // node 0 row
    float s1c = s1[0];
    int   node = 0;

#pragma unroll
    for (int l = 0; l < FFF_LEVELS; ++l) {
        nd[l] = node;

        // issue both children's w1 gathers BEFORE the dot (no sign dep)
        u32x4 d1L, d1R;
        float s1L = 0.f, s1R = 0.f;
        if (l < FFF_LEVELS - 1) {
            const int left = 2 * node + 1;
            d1L = q1v[(size_t)left * 64 + lane];
            d1R = q1v[(size_t)(left + 1) * 64 + lane];
            s1L = s1[left];
            s1R = s1[left + 1];
        }

        // i8 dot with the current node's (already-resident) row
        int id = 0;
#pragma unroll
        for (int c = 0; c < 4; ++c) id = sdot4(xq[c], d1c[c], id);
        float p = (float)wave_sum_i(id) * (stx * s1c);

        // rare wave-uniform fp32 recompute (x reloaded from global)
        if (__builtin_expect(fabsf(p) < FFF_EPS, 0)) {
            const f32x4* w14 = reinterpret_cast<const f32x4*>(w1f + (size_t)node * FFF_NIN);
            float s = 0.f;
#pragma unroll
            for (int c = 0; c < 4; ++c) {
                const f32x4 xc = ld_nt4f(&x4[c * 64 + lane]);
                const f32x4 w  = w14[c * 64 + lane];
                s = fmaf(xc[0], w[0], s);
                s = fmaf(xc[1], w[1], s);
                s = fmaf(xc[2], w[2], s);
                s = fmaf(xc[3], w[3], s);
            }
            p = wave_sum(s);
        }

        sc[l] = p;
        const bool right = (p > 0.f);
        node = 2 * node + 1 + (right ? 1 : 0);
        if (l < FFF_LEVELS - 1) {
            d1c = right ? d1R : d1L;
            s1c = right ? s1R : s1L;
        }
    }

    // ---- epilogue: all 11 w2 gathers upfront (pure MLP), dense accum ----
    u32x4 d2[FFF_LEVELS];
#pragma unroll
    for (int l = 0; l < FFF_LEVELS; ++l)
        d2[l] = q2v[(size_t)nd[l] * 64 + lane];

    float f[FFF_LEVELS];
#pragma unroll
    for (int l = 0; l < FFF_LEVELS; ++l)
        f[l] = sc[l] * s2[nd[l]];

    f32x4 acc[4];
#pragma unroll
    for (int c = 0; c < 4; ++c) acc[c] = (f32x4)(0.f);
    float corr = 0.f;
#pragma unroll
    for (int l = 0; l < FFF_LEVELS; ++l) {
        corr = fmaf(f[l], 128.f, corr);
#pragma unroll
        for (int c = 0; c < 4; ++c) {
#pragma unroll
            for (int k = 0; k < 4; ++k)
                acc[c][k] = fmaf(f[l], ub(d2[l][c], k), acc[c][k]);
        }
    }

    // coalesced y stores, subtracting the uniform bias correction
    f32x4* y4 = reinterpret_cast<f32x4*>(y + (size_t)row * FFF_NOUT);
#pragma unroll
    for (int c = 0; c < 4; ++c) {
        f32x4 o;
#pragma unroll
        for (int k = 0; k < 4; ++k) o[k] = acc[c][k] - corr;
        y4[c * 64 + lane] = o;
    }
}

// ---- safety fallback: proven round-1 fp32 fused kernel ----
__global__ __launch_bounds__(256, 4) void fff_fused_f32(
    const float* __restrict__ x, const float* __restrict__ w1s,
    const float* __restrict__ w2s, float* __restrict__ y)
{
    const int row  = blockIdx.x * 4 + (threadIdx.x >> 6);
    const int lane = threadIdx.x & 63;
    const f32x4* x4 = reinterpret_cast<const f32x4*>(x + (size_t)row * FFF_NIN);
    f32x4 xv[4];
#pragma unroll
    for (int c = 0; c < 4; ++c) xv[c] = x4[c * 64 + lane];
    f32x4 acc[4];
#pragma unroll
    for (int c = 0; c < 4; ++c) acc[c] = (f32x4)(0.f);
    int node = 0;
#pragma unroll 1
    for (int l = 0; l < FFF_LEVELS; ++l) {
        const f32x4* w14 = reinterpret_cast<const f32x4*>(w1s + (size_t)node * FFF_NIN);
        const f32x4* w24 = reinterpret_cast<const f32x4*>(w2s + (size_t)node * FFF_NOUT);
        f32x4 wv[4], uv[4];
#pragma unroll
        for (int c = 0; c < 4; ++c) { wv[c] = w14[c * 64 + lane]; uv[c] = w24[c * 64 + lane]; }
        float p = 0.f;
#pragma unroll
        for (int c = 0; c < 4; ++c) {
            p = fmaf(xv[c][0], wv[c][0], p); p = fmaf(xv[c][1], wv[c][1], p);
            p = fmaf(xv[c][2], wv[c][2], p); p = fmaf(xv[c][3], wv[c][3], p);
        }
#pragma unroll
        for (int m = 1; m < 64; m <<= 1) p += __shfl_xor(p, m, 64);
#pragma unroll
        for (int c = 0; c < 4; ++c) {
            acc[c][0] = fmaf(p, uv[c][0], acc[c][0]); acc[c][1] = fmaf(p, uv[c][1], acc[c][1]);
            acc[c][2] = fmaf(p, uv[c][2], acc[c][2]); acc[c][3] = fmaf(p, uv[c][3], acc[c][3]);
        }
        node = node * 2 + 1 + ((p > 0.f) ? 1 : 0);
    }
    f32x4* y4 = reinterpret_cast<f32x4*>(y + (size_t)row * FFF_NOUT);
#pragma unroll
    for (int c = 0; c < 4; ++c) y4[c * 64 + lane] = acc[c];
}

extern "C" void kernel_launch(void* const* d_in, const int* in_sizes, int n_in,
                              void* d_out, int out_size, void* d_ws, size_t ws_size,
                              hipStream_t stream) {
    const float* x   = (const float*)d_in[0];
    const float* w1s = (const float*)d_in[1];
    const float* w2s = (const float*)d_in[2];
    float* y = (float*)d_out;

    // ws layout (16B-aligned blocks): s1 | s2 | q1 | q2
    const size_t sc_bytes = 8192;                              // 2047 floats, padded
    const size_t q_bytes  = (size_t)FFF_NODES * 1024;          // 2,096,128
    const size_t need = 2 * sc_bytes + 2 * q_bytes;            // ~4.21 MB

    if (ws_size >= need) {
        float* s1 = (float*)d_ws;
        float* s2 = (float*)((char*)d_ws + sc_bytes);
        unsigned char* q1 = (unsigned char*)d_ws + 2 * sc_bytes;
        unsigned char* q2 = q1 + q_bytes;
        fff_quant_u8<<<FFF_NODES, 256, 0, stream>>>(w1s, w2s, q1, q2, s1, s2);
        fff_main_u8<<<FFF_BATCH / 4, 256, 0, stream>>>(x, q1, s1, w1s, q2, s2, y);
    } else {
        fff_fused_f32<<<FFF_BATCH / 4, 256, 0, stream>>>(x, w1s, w2s, y);
    }
}

// Round 16
// 82.721 us; speedup vs baseline: 1.2716x; 1.2716x over previous
//
#include <hip/hip_runtime.h>

// FFF tree traversal, round 16: r13 kernel VERBATIM (proven 75.6us main,
// fastest so far) + two zero-traffic overlap levers:
//  (a) __launch_bounds__(256, 8): VGPR=36 fits 8 waves/SIMD (64-VGPR
//      budget). r13 ran ~4.6 resident waves against an ~800cy per-level
//      chain (520 cy/level-iter measured per SIMD) -> double the overlap.
//  (b) nontemporal y stores: y write-allocations (128 MB) were evicting
//      the 4.2 MB weight set from each XCD L2, pushing gathers to L3
//      (~800cy). nt keeps L2 for weights. (r2's "nt regression" was later
//      re-attributed to spill; these stores are full-line coalesced.
//      Tripwire: WRITE_SIZE must stay exactly 131072 KB.)
// Both-children prefetch is dead (r11, r15: extra gather traffic always
// loses). ILP2 is dead (r2/r5/r6 spill, r14 occupancy). 1 row/wave, TLP.
// Frozen: i8 x + sdot4 dot, DPP reduces, next-level load before y-accum,
// biased-u8 w2 + corr, EPS=0.035 fp32 fallback (x reloaded), nt x loads.

typedef float        f32x4 __attribute__((ext_vector_type(4)));
typedef unsigned int u32x4 __attribute__((ext_vector_type(4)));

#define FFF_BATCH  32768
#define FFF_NIN    1024
#define FFF_NOUT   1024
#define FFF_LEVELS 11
#define FFF_NODES  2047
#define FFF_EPS    0.035f

__device__ __forceinline__ f32x4 ld_nt4f(const f32x4* p) { return __builtin_nontemporal_load(p); }
__device__ __forceinline__ float ub(unsigned d, int k) {
    return (float)((d >> (8 * k)) & 0xffu);   // -> v_cvt_f32_ubyte[k]
}

__device__ __forceinline__ int sdot4(unsigned a, unsigned b, int c) {
#if __has_builtin(__builtin_amdgcn_sdot4)
    return __builtin_amdgcn_sdot4((int)a, (int)b, c, false);
#else
#pragma unroll
    for (int k = 0; k < 4; ++k) {
        const int ai = (int)(a << (24 - 8 * k)) >> 24;
        const int bi = (int)(b << (24 - 8 * k)) >> 24;
        c += ai * bi;
    }
    return c;
#endif
}

template<int CTRL>
__device__ __forceinline__ float dpp_add(float v) {
    const int t = __builtin_amdgcn_update_dpp(0, __float_as_int(v), CTRL, 0xF, 0xF, true);
    return v + __int_as_float(t);
}
__device__ __forceinline__ float wave_sum(float v) {
    v = dpp_add<0x111>(v); v = dpp_add<0x112>(v);
    v = dpp_add<0x114>(v); v = dpp_add<0x118>(v);
    v = dpp_add<0x142>(v); v = dpp_add<0x143>(v);
    return __int_as_float(__builtin_amdgcn_readlane(__float_as_int(v), 63));
}
template<int CTRL>
__device__ __forceinline__ int dpp_addi(int v) {
    return v + __builtin_amdgcn_update_dpp(0, v, CTRL, 0xF, 0xF, true);
}
__device__ __forceinline__ int wave_sum_i(int v) {
    v = dpp_addi<0x111>(v); v = dpp_addi<0x112>(v);
    v = dpp_addi<0x114>(v); v = dpp_addi<0x118>(v);
    v = dpp_addi<0x142>(v); v = dpp_addi<0x143>(v);
    return __builtin_amdgcn_readlane(v, 63);
}
template<int CTRL>
__device__ __forceinline__ float dpp_max(float v) {
    const int t = __builtin_amdgcn_update_dpp(0, __float_as_int(v), CTRL, 0xF, 0xF, true);
    return fmaxf(v, __int_as_float(t));
}
__device__ __forceinline__ float wave_max(float v) {   // v >= 0
    v = dpp_max<0x111>(v); v = dpp_max<0x112>(v);
    v = dpp_max<0x114>(v); v = dpp_max<0x118>(v);
    v = dpp_max<0x142>(v); v = dpp_max<0x143>(v);
    return __int_as_float(__builtin_amdgcn_readlane(__float_as_int(v), 63));
}

// ---- prep: w1 -> signed i8, w2 -> biased u8 (one block per node) ----
// byte b = 4*t + k of node's 1024B row <- src elem 256*(t&3) + 4*(t>>2) + k,
// so in main, lane's dwords 4*lane..+3 pair with xq[c][k] <- x[256c+4*lane+k].
__global__ void fff_quant_u8(const float* __restrict__ w1, const float* __restrict__ w2,
                             unsigned char* __restrict__ q1, unsigned char* __restrict__ q2,
                             float* __restrict__ s1, float* __restrict__ s2)
{
    const int node = blockIdx.x;
    const int t    = threadIdx.x;          // 256
    const int wave = t >> 6;
    const int lane = t & 63;

    const f32x4* r1 = reinterpret_cast<const f32x4*>(w1 + (size_t)node * FFF_NIN);
    const f32x4* r2 = reinterpret_cast<const f32x4*>(w2 + (size_t)node * FFF_NOUT);
    const int si = 64 * (t & 3) + (t >> 2);
    const f32x4 v1 = r1[si];
    const f32x4 v2 = r2[si];

    float m1 = 0.f, m2 = 0.f;
#pragma unroll
    for (int k = 0; k < 4; ++k) {
        m1 = fmaxf(m1, fabsf(v1[k]));
        m2 = fmaxf(m2, fabsf(v2[k]));
    }
#pragma unroll
    for (int m = 1; m < 64; m <<= 1) {
        m1 = fmaxf(m1, __shfl_xor(m1, m, 64));
        m2 = fmaxf(m2, __shfl_xor(m2, m, 64));
    }
    __shared__ float sm1[4], sm2[4];
    if (lane == 0) { sm1[wave] = m1; sm2[wave] = m2; }
    __syncthreads();
    m1 = fmaxf(fmaxf(sm1[0], sm1[1]), fmaxf(sm1[2], sm1[3]));
    m2 = fmaxf(fmaxf(sm2[0], sm2[1]), fmaxf(sm2[2], sm2[3]));

    const float st1 = (m1 > 0.f) ? m1 / 127.f : 1.f;
    const float st2 = (m2 > 0.f) ? m2 / 127.f : 1.f;
    if (t == 0) { s1[node] = st1; s2[node] = st2; }

    unsigned d1 = 0, d2 = 0;
#pragma unroll
    for (int k = 0; k < 4; ++k) {
        const int i1 = (int)rintf(v1[k] / st1);         // signed, [-127,127]
        const int u2 = (int)rintf(v2[k] / st2) + 128;   // biased, [1,255]
        d1 |= ((unsigned)i1 & 0xffu) << (8 * k);
        d2 |= ((unsigned)u2 & 0xffu) << (8 * k);
    }
    reinterpret_cast<unsigned*>(q1)[(size_t)node * 256 + t] = d1;
    reinterpret_cast<unsigned*>(q2)[(size_t)node * 256 + t] = d2;
}

// ---- main fused kernel: 1 row/wave, rolled level loop, 8 waves/EU ----
__global__ __launch_bounds__(256, 8) void fff_main_u8(
    const float*         __restrict__ x,
    const unsigned char* __restrict__ q1,
    const float*         __restrict__ s1,
    const float*         __restrict__ w1f,   // fp32 w1 for the EPS fallback
    const unsigned char* __restrict__ q2,
    const float*         __restrict__ s2,
    float*               __restrict__ y)
{
    const int row  = blockIdx.x * 4 + (threadIdx.x >> 6);
    const int lane = threadIdx.x & 63;

    // coalesced x: xv[c] = elements 256c + 4*lane ..+3
    const f32x4* x4 = reinterpret_cast<const f32x4*>(x + (size_t)row * FFF_NIN);
    f32x4 xv[4];
#pragma unroll
    for (int c = 0; c < 4; ++c) xv[c] = ld_nt4f(&x4[c * 64 + lane]);

    // per-row i8 quantization of x (uniform scale via DPP max-reduce)
    float mx = 0.f;
#pragma unroll
    for (int c = 0; c < 4; ++c)
#pragma unroll
        for (int k = 0; k < 4; ++k) mx = fmaxf(mx, fabsf(xv[c][k]));
    mx = wave_max(mx);
    const float stx = (mx > 0.f) ? mx / 127.f : 1.f;
    const float inv = (mx > 0.f) ? 127.f / mx : 0.f;

    unsigned xq[4];
#pragma unroll
    for (int c = 0; c < 4; ++c) {
        const int a0 = (int)rintf(xv[c][0] * inv);
        const int a1 = (int)rintf(xv[c][1] * inv);
        const int a2 = (int)rintf(xv[c][2] * inv);
        const int a3 = (int)rintf(xv[c][3] * inv);
        xq[c] = ((unsigned)a0 & 0xffu) | (((unsigned)a1 & 0xffu) << 8) |
                (((unsigned)a2 & 0xffu) << 16) | (((unsigned)a3 & 0xffu) << 24);
    }

    f32x4 acc[4];
#pragma unroll
    for (int c = 0; c < 4; ++c) acc[c] = (f32x4)(0.f);
    float corr = 0.f;

    const u32x4* q1v = reinterpret_cast<const u32x4*>(q1);  // node*64 + lane
    const u32x4* q2v = reinterpret_cast<const u32x4*>(q2);

    int node = 0;
    u32x4 d1 = q1v[lane];
    u32x4 d2 = q2v[lane];
    float sc1 = s1[0];
    float sc2 = s2[0];

#pragma unroll 1
    for (int l = 0; l < FFF_LEVELS; ++l) {
        // ---- i8 dot: 4 sdot4 per lane, exact i32 ----
        int idot = 0;
#pragma unroll
        for (int c = 0; c < 4; ++c) idot = sdot4(xq[c], d1[c], idot);

        // ---- DPP integer reduce; score uniform ----
        float p = (float)wave_sum_i(idot) * (stx * sc1);

        // ---- rare wave-uniform fp32 recompute for near-zero scores ----
        if (__builtin_expect(fabsf(p) < FFF_EPS, 0)) {
            const f32x4* w14 = reinterpret_cast<const f32x4*>(w1f + (size_t)node * FFF_NIN);
            float s = 0.f;
#pragma unroll
            for (int c = 0; c < 4; ++c) {
                const f32x4 w = w14[c * 64 + lane];
                s = fmaf(xv[c][0], w[0], s);
                s = fmaf(xv[c][1], w[1], s);
                s = fmaf(xv[c][2], w[2], s);
                s = fmaf(xv[c][3], w[3], s);
            }
            p = wave_sum(s);
        }

        // ---- advance + issue next level's loads before the y-accum ----
        const int next = 2 * node + 1 + ((p > 0.f) ? 1 : 0);
        u32x4 nd1 = d1, nd2 = d2;
        float ns1 = sc1, ns2 = sc2;
        if (l < FFF_LEVELS - 1) {
            const int un = __builtin_amdgcn_readfirstlane(next);
            nd1 = q1v[(size_t)un * 64 + lane];
            nd2 = q2v[(size_t)un * 64 + lane];
            ns1 = s1[un];
            ns2 = s2[un];
        }

        // ---- y accumulate (hides the child-load latency) ----
        const float s2l = p * sc2;
        corr = fmaf(s2l, 128.f, corr);
#pragma unroll
        for (int c = 0; c < 4; ++c) {
#pragma unroll
            for (int k = 0; k < 4; ++k)
                acc[c][k] = fmaf(s2l, ub(d2[c], k), acc[c][k]);
        }

        node = next;
        d1 = nd1; d2 = nd2; sc1 = ns1; sc2 = ns2;
    }

    // coalesced nontemporal y stores (full 128B lines; keep L2 for weights)
    f32x4* y4 = reinterpret_cast<f32x4*>(y + (size_t)row * FFF_NOUT);
#pragma unroll
    for (int c = 0; c < 4; ++c) {
        f32x4 o;
        o[0] = acc[c][0] - corr; o[1] = acc[c][1] - corr;
        o[2] = acc[c][2] - corr; o[3] = acc[c][3] - corr;
        __builtin_nontemporal_store(o, &y4[c * 64 + lane]);
    }
}

// ---- safety fallback: proven round-1 fp32 fused kernel ----
__global__ __launch_bounds__(256, 4) void fff_fused_f32(
    const float* __restrict__ x, const float* __restrict__ w1s,
    const float* __restrict__ w2s, float* __restrict__ y)
{
    const int row  = blockIdx.x * 4 + (threadIdx.x >> 6);
    const int lane = threadIdx.x & 63;
    const f32x4* x4 = reinterpret_cast<const f32x4*>(x + (size_t)row * FFF_NIN);
    f32x4 xv[4];
#pragma unroll
    for (int c = 0; c < 4; ++c) xv[c] = x4[c * 64 + lane];
    f32x4 acc[4];
#pragma unroll
    for (int c = 0; c < 4; ++c) acc[c] = (f32x4)(0.f);
    int node = 0;
#pragma unroll 1
    for (int l = 0; l < FFF_LEVELS; ++l) {
        const f32x4* w14 = reinterpret_cast<const f32x4*>(w1s + (size_t)node * FFF_NIN);
        const f32x4* w24 = reinterpret_cast<const f32x4*>(w2s + (size_t)node * FFF_NOUT);
        f32x4 wv[4], uv[4];
#pragma unroll
        for (int c = 0; c < 4; ++c) { wv[c] = w14[c * 64 + lane]; uv[c] = w24[c * 64 + lane]; }
        float p = 0.f;
#pragma unroll
        for (int c = 0; c < 4; ++c) {
            p = fmaf(xv[c][0], wv[c][0], p); p = fmaf(xv[c][1], wv[c][1], p);
            p = fmaf(xv[c][2], wv[c][2], p); p = fmaf(xv[c][3], wv[c][3], p);
        }
#pragma unroll
        for (int m = 1; m < 64; m <<= 1) p += __shfl_xor(p, m, 64);
#pragma unroll
        for (int c = 0; c < 4; ++c) {
            acc[c][0] = fmaf(p, uv[c][0], acc[c][0]); acc[c][1] = fmaf(p, uv[c][1], acc[c][1]);
            acc[c][2] = fmaf(p, uv[c][2], acc[c][2]); acc[c][3] = fmaf(p, uv[c][3], acc[c][3]);
        }
        node = node * 2 + 1 + ((p > 0.f) ? 1 : 0);
    }
    f32x4* y4 = reinterpret_cast<f32x4*>(y + (size_t)row * FFF_NOUT);
#pragma unroll
    for (int c = 0; c < 4; ++c) y4[c * 64 + lane] = acc[c];
}

extern "C" void kernel_launch(void* const* d_in, const int* in_sizes, int n_in,
                              void* d_out, int out_size, void* d_ws, size_t ws_size,
                              hipStream_t stream) {
    const float* x   = (const float*)d_in[0];
    const float* w1s = (const float*)d_in[1];
    const float* w2s = (const float*)d_in[2];
    float* y = (float*)d_out;

    // ws layout (16B-aligned blocks): s1 | s2 | q1 | q2
    const size_t sc_bytes = 8192;                              // 2047 floats, padded
    const size_t q_bytes  = (size_t)FFF_NODES * 1024;          // 2,096,128
    const size_t need = 2 * sc_bytes + 2 * q_bytes;            // ~4.21 MB

    if (ws_size >= need) {
        float* s1 = (float*)d_ws;
        float* s2 = (float*)((char*)d_ws + sc_bytes);
        unsigned char* q1 = (unsigned char*)d_ws + 2 * sc_bytes;
        unsigned char* q2 = q1 + q_bytes;
        fff_quant_u8<<<FFF_NODES, 256, 0, stream>>>(w1s, w2s, q1, q2, s1, s2);
        fff_main_u8<<<FFF_BATCH / 4, 256, 0, stream>>>(x, q1, s1, w1s, q2, s2, y);
    } else {
        fff_fused_f32<<<FFF_BATCH / 4, 256, 0, stream>>>(x, w1s, w2s, y);
    }
}